// Round 2
// baseline (3411.647 us; speedup 1.0000x reference)
//
#include <hip/hip_runtime.h>
#include <hip/hip_bf16.h>
#include <math.h>

#define LSEQ 2048
#define DMODEL 768
#define DINNER 1536
#define DSTATE 16
#define DTRANK 48
#define NLAYER 4
#define XDBL_W 80   /* DTRANK + 2*DSTATE */
#define CH 64       /* scan chunks */
#define SLEN 32     /* steps per chunk, CH*SLEN == LSEQ */

typedef __attribute__((ext_vector_type(4))) float f32x4;
typedef __attribute__((ext_vector_type(8))) short short8;
typedef __attribute__((ext_vector_type(8))) __bf16 bf16x8;
typedef __attribute__((ext_vector_type(4))) unsigned short us4;

__device__ inline float softplus_f(float x) {
    return fmaxf(x, 0.f) + log1pf(expf(-fabsf(x)));
}
__device__ inline float silu_f(float x) {
    return x / (1.f + expf(-x));
}

/* bf16 round-to-nearest-even via bit ops */
__device__ inline unsigned short f2bf(float f) {
    unsigned int u = __float_as_uint(f);
    unsigned int r = (u + 0x7fffu + ((u >> 16) & 1u)) >> 16;
    return (unsigned short)r;
}
__device__ inline float bf2f(unsigned short b) {
    return __uint_as_float((unsigned int)b << 16);
}

__device__ inline f32x4 mfma_bf16_16x16x32(short8 a, short8 b, f32x4 c) {
    return __builtin_amdgcn_mfma_f32_16x16x32_bf16(
        __builtin_bit_cast(bf16x8, a), __builtin_bit_cast(bf16x8, b), c, 0, 0, 0);
}

#define GLDS16(gp, lp) __builtin_amdgcn_global_load_lds( \
    (const __attribute__((address_space(1))) void*)(gp), \
    (__attribute__((address_space(3))) void*)(lp), 16, 0, 0)

/* ---------------- embedding gather ---------------- */
__global__ __launch_bounds__(256) void embed_kernel(
    const int* __restrict__ ids, const float* __restrict__ emb,
    float* __restrict__ x)
{
    int l = blockIdx.x;
    int id = ids[l];
    const float* src = emb + (size_t)id * DMODEL;
    float* dst = x + (size_t)l * DMODEL;
    for (int j = threadIdx.x; j < DMODEL; j += 256) dst[j] = src[j];
}

/* ---------------- rmsnorm -> split bf16 hi/lo (block per row) ---------------- */
__global__ __launch_bounds__(256) void rmsnorm_split_kernel(
    const float* __restrict__ x, const float* __restrict__ w,
    unsigned short* __restrict__ ohi, unsigned short* __restrict__ olo)
{
    int row = blockIdx.x;
    const float* xr = x + (size_t)row * DMODEL;
    float ss = 0.f;
    for (int j = threadIdx.x; j < DMODEL; j += 256) { float v = xr[j]; ss += v * v; }
    __shared__ float red[256];
    red[threadIdx.x] = ss;
    __syncthreads();
    for (int s = 128; s > 0; s >>= 1) {
        if (threadIdx.x < s) red[threadIdx.x] += red[threadIdx.x + s];
        __syncthreads();
    }
    float scale = rsqrtf(red[0] / DMODEL + 1e-5f);
    for (int j = threadIdx.x; j < DMODEL; j += 256) {
        float v = xr[j] * scale * w[j];
        unsigned short hv = f2bf(v);
        ohi[(size_t)row * DMODEL + j] = hv;
        olo[(size_t)row * DMODEL + j] = f2bf(v - bf2f(hv));
    }
}

/* ---------------- split f32 -> (bf16 hi, bf16 lo), tail zero-padded ------- */
__global__ __launch_bounds__(256) void split_bf16_kernel(
    const float* __restrict__ src, unsigned short* __restrict__ hi,
    unsigned short* __restrict__ lo, long long srcElems, long long totElems)
{
    long long idx = ((long long)blockIdx.x * 256 + threadIdx.x) * 4;
    if (idx >= totElems) return;
    float4 v = make_float4(0.f, 0.f, 0.f, 0.f);
    if (idx < srcElems) v = *(const float4*)(src + idx);
    unsigned short h0 = f2bf(v.x), h1 = f2bf(v.y), h2 = f2bf(v.z), h3 = f2bf(v.w);
    us4 hv = { h0, h1, h2, h3 };
    us4 lv = { f2bf(v.x - bf2f(h0)), f2bf(v.y - bf2f(h1)),
               f2bf(v.z - bf2f(h2)), f2bf(v.w - bf2f(h3)) };
    *(us4*)(hi + idx) = hv;
    *(us4*)(lo + idx) = lv;
}

/* ---------------- W_delta = dtw(1536x48) @ xpw48(48x1536), split output ----
 * Folds dt_proj into x_proj: delta = softplus(u @ W_delta^T + b).
 * Tiled 64x64, K=48 staged whole in LDS (+pad for bank spread). */
__global__ __launch_bounds__(256) void wdelta_kernel(
    const float* __restrict__ dtw, const float* __restrict__ xpw,
    unsigned short* __restrict__ whi, unsigned short* __restrict__ wlo)
{
    __shared__ float As[64][49];   /* dtw tile rows i, K */
    __shared__ float Bs[48][65];   /* xpw48 K x cols j */
    int tid = threadIdx.x;
    int tx = tid & 15, ty = tid >> 4;
    int i0 = blockIdx.y * 64, j0 = blockIdx.x * 64;
    for (int t = tid; t < 64 * 48; t += 256)
        As[t / 48][t % 48] = dtw[(size_t)(i0 + t / 48) * DTRANK + (t % 48)];
    for (int t = tid; t < 48 * 64; t += 256)
        Bs[t / 64][t % 64] = xpw[(size_t)(t / 64) * DINNER + j0 + (t % 64)];
    __syncthreads();
    float acc[4][4];
#pragma unroll
    for (int i = 0; i < 4; ++i)
#pragma unroll
        for (int j = 0; j < 4; ++j) acc[i][j] = 0.f;
    for (int k = 0; k < 48; ++k) {
        float a[4], b[4];
#pragma unroll
        for (int i = 0; i < 4; ++i) a[i] = As[ty * 4 + i][k];
#pragma unroll
        for (int j = 0; j < 4; ++j) b[j] = Bs[k][tx * 4 + j];
#pragma unroll
        for (int i = 0; i < 4; ++i)
#pragma unroll
            for (int j = 0; j < 4; ++j) acc[i][j] += a[i] * b[j];
    }
#pragma unroll
    for (int i = 0; i < 4; ++i)
#pragma unroll
        for (int j = 0; j < 4; ++j) {
            size_t off = (size_t)(i0 + ty * 4 + i) * DINNER + j0 + tx * 4 + j;
            unsigned short h = f2bf(acc[i][j]);
            whi[off] = h;
            wlo[off] = f2bf(acc[i][j] - bf2f(h));
        }
}

/* ---------------- unified split-bf16 MFMA GEMM ----------------
 * C[2048, Nreal] = (Ah+Al)(Bh+Bl)^T approx (3 terms: AhBh + AlBh + AhBl),
 * A row stride = K, B row stride = K, B has ceil(N/128)*128 rows (pad zeroed).
 * mode 0: store  | mode 1: softplus(acc + bias[n]) | mode 2: C += acc
 * 128x128 tile, 4 waves (2x2 of 64x64), mfma_f32_16x16x32_bf16,
 * global_load_lds width-16 staging (linear LDS dest), chunk-XOR swizzle
 * applied to BOTH global source and ds_read side (rule 21): spreads the
 * 16-row x 64B-stride fragment read from 8-way to 2-way (free) conflicts.
 * 1D grid with bijective XCD chunk remap (gridDim.x % 8 == 0), row-tile
 * fastest so the blocks sharing a B col-panel land on one XCD's L2. */
__global__ __launch_bounds__(256) void gemm_mfma_split(
    const unsigned short* __restrict__ Ah, const unsigned short* __restrict__ Al,
    const unsigned short* __restrict__ Bh, const unsigned short* __restrict__ Bl,
    float* __restrict__ C, int mtiles, int Nreal, int K, int ldc, int mode,
    const float* __restrict__ bias)
{
    __shared__ unsigned short As[128 * 32];  /* [row][32k], 64 B rows */
    __shared__ unsigned short Bs[128 * 32];
    int tid = threadIdx.x;
    int lane = tid & 63;
    int wid = tid >> 6;
    int wrow = wid >> 1, wcol = wid & 1;

    int chunk = gridDim.x >> 3;                 /* grid always %8 == 0 */
    int wg = (blockIdx.x & 7) * chunk + (blockIdx.x >> 3);
    int brow0 = (wg % mtiles) * 128;
    int bcol0 = (wg / mtiles) * 128;

    f32x4 acc[4][4];
#pragma unroll
    for (int m = 0; m < 4; ++m)
#pragma unroll
        for (int n = 0; n < 4; ++n) acc[m][n] = (f32x4){ 0.f, 0.f, 0.f, 0.f };

    /* staging: wave w covers local rows [w*32, w*32+32), 2 issues of 16 rows;
     * lane -> row += lane>>2, chunk (lane&3); source chunk XOR'd by (row>>1)&3
     * so the linear LDS write realizes the swizzled layout. */
    int rl0 = wid * 32 + (lane >> 2);
    char* lbaseA = (char*)As + wid * 2048;
    char* lbaseB = (char*)Bs + wid * 2048;

    for (int vb = 0; vb < 3; ++vb) {
        const unsigned short* Ab = (vb == 1) ? Al : Ah;
        const unsigned short* Bb = (vb == 2) ? Bl : Bh;
        for (int k0 = 0; k0 < K; k0 += 32) {
#pragma unroll
            for (int j = 0; j < 2; ++j) {
                int rl = rl0 + j * 16;
                int cg = ((lane & 3) ^ ((rl >> 1) & 3)) * 8;
                GLDS16(Ab + (size_t)(brow0 + rl) * K + k0 + cg, lbaseA + j * 1024);
                GLDS16(Bb + (size_t)(bcol0 + rl) * K + k0 + cg, lbaseB + j * 1024);
            }
            __syncthreads();   /* drains vmcnt before LDS reads */
            short8 af[4], bfr[4];
#pragma unroll
            for (int m = 0; m < 4; ++m) {
                int r = wrow * 64 + m * 16 + (lane & 15);
                af[m] = *(const short8*)(As + r * 32 + (((lane >> 4) ^ ((r >> 1) & 3)) * 8));
            }
#pragma unroll
            for (int n = 0; n < 4; ++n) {
                int r = wcol * 64 + n * 16 + (lane & 15);
                bfr[n] = *(const short8*)(Bs + r * 32 + (((lane >> 4) ^ ((r >> 1) & 3)) * 8));
            }
#pragma unroll
            for (int m = 0; m < 4; ++m)
#pragma unroll
                for (int n = 0; n < 4; ++n)
                    acc[m][n] = mfma_bf16_16x16x32(af[m], bfr[n], acc[m][n]);
            __syncthreads();   /* protect LDS before next stage */
        }
    }

    /* C/D lane map (m89-verified): row = (lane>>4)*4 + i, col = lane&15 */
    int r0 = brow0 + wrow * 64 + (lane >> 4) * 4;
    int c0 = bcol0 + wcol * 64 + (lane & 15);
#pragma unroll
    for (int m = 0; m < 4; ++m)
#pragma unroll
        for (int n = 0; n < 4; ++n) {
            int col = c0 + n * 16;
            if (col >= Nreal) continue;
#pragma unroll
            for (int i = 0; i < 4; ++i) {
                int row = r0 + m * 16 + i;
                float v = acc[m][n][i];
                if (mode == 1) v = softplus_f(v + bias[col]);
                else if (mode == 2) v += C[(size_t)row * ldc + col];
                C[(size_t)row * ldc + col] = v;
            }
        }
}

/* ---------------- depthwise causal conv (k=4) + silu, fused u split ------- */
__global__ __launch_bounds__(256) void conv_silu_kernel(
    const float* __restrict__ xr, const float* __restrict__ cw,
    const float* __restrict__ cb, float* __restrict__ u,
    unsigned short* __restrict__ uhi, unsigned short* __restrict__ ulo)
{
    int idx = blockIdx.x * 256 + threadIdx.x;
    if (idx >= LSEQ * DINNER) return;
    int l = idx / DINNER;
    int d = idx - l * DINNER;
    float s = cb[d];
#pragma unroll
    for (int t = 0; t < 4; ++t) {
        int ll = l - 3 + t;
        if (ll >= 0) s += xr[(size_t)ll * (2 * DINNER) + d] * cw[d * 4 + t];
    }
    float v = silu_f(s);
    u[idx] = v;
    unsigned short h = f2bf(v);
    uhi[idx] = h;
    ulo[idx] = f2bf(v - bf2f(h));
}

/* ---------------- A = -exp(A_log), all layers at once ---------------- */
__global__ __launch_bounds__(256) void neg_exp_kernel(
    const float* __restrict__ a, float* __restrict__ o, int n)
{
    int i = blockIdx.x * 256 + threadIdx.x;
    if (i < n) o[i] = -expf(a[i]);
}

/* ---------------- chunked selective scan ---------------- */
__global__ __launch_bounds__(256) void scan_phase1(
    const float* __restrict__ delta, const float* __restrict__ u,
    const float* __restrict__ xdbl, const float* __restrict__ Aneg,
    float* __restrict__ cA, float* __restrict__ cB)
{
    int tid = threadIdx.x;
    int n = tid & 15;
    int d = blockIdx.x * 16 + (tid >> 4);
    int c = blockIdx.y;
    float Av = Aneg[d * DSTATE + n];
    float h = 0.f, ap = 1.f;
    int l = c * SLEN;
    for (int s = 0; s < SLEN; ++s, ++l) {
        float dt = delta[(size_t)l * DINNER + d];
        float uv = u[(size_t)l * DINNER + d];
        float Bv = xdbl[l * XDBL_W + DTRANK + n];
        float a = expf(dt * Av);
        h = a * h + dt * Bv * uv;
        ap *= a;
    }
    size_t off = ((size_t)c * DINNER + d) * DSTATE + n;
    cA[off] = ap;
    cB[off] = h;
}

__global__ __launch_bounds__(256) void scan_phase2(
    const float* __restrict__ cA, const float* __restrict__ cB,
    float* __restrict__ hs)
{
    int idx = blockIdx.x * 256 + threadIdx.x; /* over DINNER*DSTATE */
    float h = 0.f;
    for (int c = 0; c < CH; ++c) {
        size_t off = (size_t)c * DINNER * DSTATE + idx;
        hs[off] = h;
        h = cA[off] * h + cB[off];
    }
}

__global__ __launch_bounds__(256) void scan_phase3(
    const float* __restrict__ delta, const float* __restrict__ u,
    const float* __restrict__ xdbl, const float* __restrict__ Aneg,
    const float* __restrict__ hs, const float* __restrict__ Dp,
    const float* __restrict__ xr,
    unsigned short* __restrict__ yhi, unsigned short* __restrict__ ylo)
{
    int tid = threadIdx.x;
    int n = tid & 15;
    int d = blockIdx.x * 16 + (tid >> 4);
    int c = blockIdx.y;
    float Av = Aneg[d * DSTATE + n];
    float Dv = Dp[d];
    float h = hs[((size_t)c * DINNER + d) * DSTATE + n];
    int l = c * SLEN;
    for (int s = 0; s < SLEN; ++s, ++l) {
        float dt = delta[(size_t)l * DINNER + d];
        float uv = u[(size_t)l * DINNER + d];
        float Bv = xdbl[l * XDBL_W + DTRANK + n];
        float Cv = xdbl[l * XDBL_W + DTRANK + DSTATE + n];
        float a = expf(dt * Av);
        h = a * h + dt * Bv * uv;
        float p = h * Cv;
        p += __shfl_down(p, 8, 16);
        p += __shfl_down(p, 4, 16);
        p += __shfl_down(p, 2, 16);
        p += __shfl_down(p, 1, 16);
        if (n == 0) {
            float r = xr[(size_t)l * (2 * DINNER) + DINNER + d];
            float vy = (p + uv * Dv) * silu_f(r);
            size_t oy = (size_t)l * DINNER + d;
            unsigned short hv = f2bf(vy);
            yhi[oy] = hv;
            ylo[oy] = f2bf(vy - bf2f(hv));
        }
    }
}

extern "C" void kernel_launch(void* const* d_in, const int* in_sizes, int n_in,
                              void* d_out, int out_size, void* d_ws, size_t ws_size,
                              hipStream_t stream)
{
    const int*   ids   = (const int*)d_in[0];
    const float* emb   = (const float*)d_in[1];
    const float* in_w  = (const float*)d_in[2];
    const float* cw    = (const float*)d_in[3];
    const float* cb    = (const float*)d_in[4];
    const float* xpw   = (const float*)d_in[5];
    const float* dtw   = (const float*)d_in[6];
    const float* dtb   = (const float*)d_in[7];
    const float* A_log = (const float*)d_in[8];
    const float* Dp    = (const float*)d_in[9];
    const float* ow    = (const float*)d_in[10];
    const float* nw    = (const float*)d_in[11];
    const float* nfw   = (const float*)d_in[12];
    float* out = (float*)d_out;

    const int VOCAB = in_sizes[1] / DMODEL; /* 50264 */
    const int Npad = ((VOCAB + 127) / 128) * 128; /* 50304 */

    float* ws = (float*)d_ws;
    size_t o = 0;
    float* x     = ws + o; o += (size_t)LSEQ * DMODEL;
    float* xr    = ws + o; o += (size_t)LSEQ * 2 * DINNER;
    float* u     = ws + o; o += (size_t)LSEQ * DINNER;
    float* xdbl  = ws + o; o += (size_t)LSEQ * XDBL_W;
    float* delta = ws + o; o += (size_t)LSEQ * DINNER;
    float* Aneg  = ws + o; o += (size_t)NLAYER * DINNER * DSTATE;
    float* cA    = ws + o; o += (size_t)CH * DINNER * DSTATE;
    float* cB    = ws + o; o += (size_t)CH * DINNER * DSTATE;
    float* hsb   = ws + o; o += (size_t)CH * DINNER * DSTATE;
    /* bf16 buffers (2B/elem, counted in float units) */
    unsigned short* hhi = (unsigned short*)(ws + o); o += (size_t)LSEQ * DMODEL / 2;
    unsigned short* hlo = (unsigned short*)(ws + o); o += (size_t)LSEQ * DMODEL / 2;
    unsigned short* uhi = (unsigned short*)(ws + o); o += (size_t)LSEQ * DINNER / 2;
    unsigned short* ulo = (unsigned short*)(ws + o); o += (size_t)LSEQ * DINNER / 2;
    unsigned short* yhi = (unsigned short*)(ws + o); o += (size_t)LSEQ * DINNER / 2;
    unsigned short* ylo = (unsigned short*)(ws + o); o += (size_t)LSEQ * DINNER / 2;
    unsigned short* Bhi = (unsigned short*)(ws + o); o += (size_t)Npad * DMODEL / 2;
    unsigned short* Blo = (unsigned short*)(ws + o); o += (size_t)Npad * DMODEL / 2;
    /* per-layer weight splits, reused across layers (stream-ordered) */
    unsigned short* wAh = (unsigned short*)(ws + o); o += (size_t)2 * DINNER * DMODEL / 2;
    unsigned short* wAl = (unsigned short*)(ws + o); o += (size_t)2 * DINNER * DMODEL / 2;
    unsigned short* wOh = (unsigned short*)(ws + o); o += (size_t)DMODEL * DINNER / 2;
    unsigned short* wOl = (unsigned short*)(ws + o); o += (size_t)DMODEL * DINNER / 2;
    unsigned short* wXh = (unsigned short*)(ws + o); o += (size_t)128 * DINNER / 2;
    unsigned short* wXl = (unsigned short*)(ws + o); o += (size_t)128 * DINNER / 2;
    unsigned short* wDh = (unsigned short*)(ws + o); o += (size_t)DINNER * DINNER / 2;
    unsigned short* wDl = (unsigned short*)(ws + o); o += (size_t)DINNER * DINNER / 2;

    /* emb -> bf16 hi/lo split (padded rows zeroed) */
    {
        long long srcE = (long long)VOCAB * DMODEL;
        long long totE = (long long)Npad * DMODEL;
        split_bf16_kernel<<<(int)((totE / 4 + 255) / 256), 256, 0, stream>>>(
            emb, Bhi, Blo, srcE, totE);
    }
    /* Aneg for all layers */
    neg_exp_kernel<<<(NLAYER * DINNER * DSTATE + 255) / 256, 256, 0, stream>>>(
        A_log, Aneg, NLAYER * DINNER * DSTATE);

    embed_kernel<<<LSEQ, 256, 0, stream>>>(ids, emb, x);

    for (int i = 0; i < NLAYER; ++i) {
        /* weight splits for this layer (reused buffers; stream-serial) */
        {
            long long e = (long long)2 * DINNER * DMODEL;
            split_bf16_kernel<<<(int)((e / 4 + 255) / 256), 256, 0, stream>>>(
                in_w + (size_t)i * e, wAh, wAl, e, e);
        }
        {
            long long e = (long long)DMODEL * DINNER;
            split_bf16_kernel<<<(int)((e / 4 + 255) / 256), 256, 0, stream>>>(
                ow + (size_t)i * e, wOh, wOl, e, e);
        }
        {
            long long srcE = (long long)XDBL_W * DINNER;
            long long totE = (long long)128 * DINNER;
            split_bf16_kernel<<<(int)((totE / 4 + 255) / 256), 256, 0, stream>>>(
                xpw + (size_t)i * srcE, wXh, wXl, srcE, totE);
        }
        wdelta_kernel<<<dim3(DINNER / 64, DINNER / 64), 256, 0, stream>>>(
            dtw + (size_t)i * DINNER * DTRANK, xpw + (size_t)i * XDBL_W * DINNER,
            wDh, wDl);

        rmsnorm_split_kernel<<<LSEQ, 256, 0, stream>>>(
            x, nw + (size_t)i * DMODEL, hhi, hlo);

        /* x_and_res = h @ in_w^T : (2048, 3072), K=768 */
        gemm_mfma_split<<<16 * (2 * DINNER / 128), 256, 0, stream>>>(
            hhi, hlo, wAh, wAl, xr, 16, 2 * DINNER, DMODEL, 2 * DINNER, 0, nullptr);

        conv_silu_kernel<<<(LSEQ * DINNER + 255) / 256, 256, 0, stream>>>(
            xr, cw + (size_t)i * DINNER * 4, cb + (size_t)i * DINNER, u, uhi, ulo);

        /* x_dbl = u @ xpw^T : (2048, 80 padded 128), K=1536 */
        gemm_mfma_split<<<16 * 1, 256, 0, stream>>>(
            uhi, ulo, wXh, wXl, xdbl, 16, XDBL_W, DINNER, XDBL_W, 0, nullptr);

        /* delta = softplus(u @ W_delta^T + dtb) : (2048, 1536), K=1536 */
        gemm_mfma_split<<<16 * (DINNER / 128), 256, 0, stream>>>(
            uhi, ulo, wDh, wDl, delta, 16, DINNER, DINNER, DINNER, 1,
            dtb + (size_t)i * DINNER);

        scan_phase1<<<dim3(DINNER / 16, CH), 256, 0, stream>>>(
            delta, u, xdbl, Aneg + (size_t)i * DINNER * DSTATE, cA, cB);
        scan_phase2<<<DINNER * DSTATE / 256, 256, 0, stream>>>(cA, cB, hsb);
        scan_phase3<<<dim3(DINNER / 16, CH), 256, 0, stream>>>(
            delta, u, xdbl, Aneg + (size_t)i * DINNER * DSTATE, hsb,
            Dp + (size_t)i * DINNER, xr, yhi, ylo);

        /* x += y @ ow^T : (2048, 768), K=1536 */
        gemm_mfma_split<<<16 * (DMODEL / 128), 256, 0, stream>>>(
            yhi, ylo, wOh, wOl, x, 16, DMODEL, DINNER, DMODEL, 2, nullptr);
    }

    rmsnorm_split_kernel<<<LSEQ, 256, 0, stream>>>(x, nfw, hhi, hlo);

    /* logits = h @ emb^T : (2048, VOCAB), K=768 */
    gemm_mfma_split<<<16 * (Npad / 128), 256, 0, stream>>>(
        hhi, hlo, Bhi, Blo, out, 16, VOCAB, DMODEL, VOCAB, 0, nullptr);
}